// Round 1
// baseline (961.107 us; speedup 1.0000x reference)
//
#include <hip/hip_runtime.h>

// Problem sizes (fixed by the reference).
#define NL 16
#define NT 2048
#define NH 2048
#define NF 512
#define NPAIR 136   // lower-triangular (s <= l) pairs: 16*17/2

typedef short bf16x8 __attribute__((ext_vector_type(8)));
typedef float f32x4 __attribute__((ext_vector_type(4)));
typedef short s16x4 __attribute__((ext_vector_type(4)));

__device__ __forceinline__ short f2bf(float f) {
  // round-to-nearest-even f32 -> bf16 (bit pattern as short)
  union { float f; unsigned u; } x; x.f = f;
  unsigned r = (x.u + 0x7fffu + ((x.u >> 16) & 1u)) >> 16;
  return (short)r;
}

// ---------------- conversion kernels ----------------

__global__ void k_cvt_f32_bf16(const float* __restrict__ src, short* __restrict__ dst, int n4) {
  int i = blockIdx.x * blockDim.x + threadIdx.x;
  const int stride = gridDim.x * blockDim.x;
  for (; i < n4; i += stride) {
    const float4 v = reinterpret_cast<const float4*>(src)[i];
    s16x4 o;
    o[0] = f2bf(v.x); o[1] = f2bf(v.y); o[2] = f2bf(v.z); o[3] = f2bf(v.w);
    reinterpret_cast<s16x4*>(dst)[i] = o;
  }
}

// Convert only the s<=l blocks of W_dec[s][l][H][F] into a packed [p][H][F] bf16 array,
// p = l*(l+1)/2 + s.
__global__ void k_cvt_wdec(const float* __restrict__ wdec, short* __restrict__ dst) {
  const int p = blockIdx.y;
  int l = 0;
  while ((l + 1) * (l + 2) / 2 <= p) ++l;
  const int s = p - l * (l + 1) / 2;
  const float* src = wdec + (size_t)(s * NL + l) * (NH * NF);
  short* d = dst + (size_t)p * (NH * NF);
  const int n4 = NH * NF / 4;  // 262144
  for (int i = blockIdx.x * blockDim.x + threadIdx.x; i < n4; i += gridDim.x * blockDim.x) {
    const float4 v = reinterpret_cast<const float4*>(src)[i];
    s16x4 o;
    o[0] = f2bf(v.x); o[1] = f2bf(v.y); o[2] = f2bf(v.z); o[3] = f2bf(v.w);
    reinterpret_cast<s16x4*>(d)[i] = o;
  }
}

// ---------------- GEMM building blocks (m97-style 128x128, BK=64, 4 waves) ----------------

// Stage a 128x64 bf16 tile (row-major, leading dim ld elements) into linear LDS [128][64].
// Each wave's global_load_lds writes lane*16B from a wave-uniform LDS base (linear layout required).
__device__ __forceinline__ void stage64(const short* gtile, int ld, short* lds, int wave, int lane) {
#pragma unroll
  for (int i = 0; i < 4; ++i) {
    const int row = i * 32 + wave * 8 + (lane >> 3);
    const int col = (lane & 7) * 8;
    __builtin_amdgcn_global_load_lds(
        (const __attribute__((address_space(1))) void*)(gtile + (size_t)row * ld + col),
        (__attribute__((address_space(3))) void*)(lds + i * 2048 + wave * 512),
        16, 0, 0);
  }
}

// One BK=64 step: 2 k-chunks x (4 A-frags, 4 B-frags, 16 MFMA).
__device__ __forceinline__ void mma_step(const short* As, const short* Bs,
                                         f32x4 acc[4][4], int wr, int wc, int lane) {
  const int r = lane & 15;
  const int ko = (lane >> 4) * 8;
#pragma unroll
  for (int kk = 0; kk < 2; ++kk) {
    bf16x8 a[4], b[4];
#pragma unroll
    for (int m = 0; m < 4; ++m)
      a[m] = *reinterpret_cast<const bf16x8*>(As + (wr * 64 + m * 16 + r) * 64 + kk * 32 + ko);
#pragma unroll
    for (int n = 0; n < 4; ++n)
      b[n] = *reinterpret_cast<const bf16x8*>(Bs + (wc * 64 + n * 16 + r) * 64 + kk * 32 + ko);
#pragma unroll
    for (int m = 0; m < 4; ++m)
#pragma unroll
      for (int n = 0; n < 4; ++n)
        acc[m][n] = __builtin_amdgcn_mfma_f32_16x16x32_bf16(a[m], b[n], acc[m][n], 0, 0, 0);
  }
}

// ---------------- encode: feats[l] = relu(x[l] @ W_enc[l]^T) ----------------

__global__ __launch_bounds__(256, 2) void k_encode(const short* __restrict__ xbf,
                                                   const short* __restrict__ webf,
                                                   float* __restrict__ feats_f32,
                                                   short* __restrict__ feats_bf) {
  __shared__ short As[128 * 64];
  __shared__ short Bs[128 * 64];
  const int l = blockIdx.z;
  const int row0 = blockIdx.y * 128;  // over T
  const int col0 = blockIdx.x * 128;  // over F
  const int tid = threadIdx.x;
  const int wave = tid >> 6, lane = tid & 63;
  const int wr = wave >> 1, wc = wave & 1;

  const short* A = xbf + (size_t)l * NT * NH + (size_t)row0 * NH;
  const short* B = webf + (size_t)l * NF * NH + (size_t)col0 * NH;

  f32x4 acc[4][4];
#pragma unroll
  for (int m = 0; m < 4; ++m)
#pragma unroll
    for (int n = 0; n < 4; ++n) {
      f32x4 z = {0.f, 0.f, 0.f, 0.f};
      acc[m][n] = z;
    }

  for (int kt = 0; kt < NH / 64; ++kt) {
    stage64(A + kt * 64, NH, As, wave, lane);
    stage64(B + kt * 64, NH, Bs, wave, lane);
    __syncthreads();
    mma_step(As, Bs, acc, wr, wc, lane);
    __syncthreads();
  }

  const int lr = (lane >> 4) * 4, lc = lane & 15;
  float* outF = feats_f32 + (size_t)l * NT * NF;
  short* outB = feats_bf + (size_t)l * NT * NF;
#pragma unroll
  for (int m = 0; m < 4; ++m) {
#pragma unroll
    for (int n = 0; n < 4; ++n) {
#pragma unroll
      for (int rg = 0; rg < 4; ++rg) {
        const int rr = row0 + wr * 64 + m * 16 + lr + rg;
        const int cc = col0 + wc * 64 + n * 16 + lc;
        float v = acc[m][n][rg];
        v = v > 0.f ? v : 0.f;  // JumpReLU threshold=0 -> relu
        outF[(size_t)rr * NF + cc] = v;
        outB[(size_t)rr * NF + cc] = f2bf(v);
      }
    }
  }
}

// ---------------- decode: recon[l] = sum_{s<=l} feats[s] @ W_dec[s,l]^T ----------------

__global__ __launch_bounds__(256, 2) void k_decode(const short* __restrict__ featsbf,
                                                   const short* __restrict__ wdbf,
                                                   float* __restrict__ recon) {
  __shared__ short As[128 * 64];
  __shared__ short Bs[128 * 64];
  const int l = (NL - 1) - blockIdx.z;  // heavy layers first (tail-straggler heuristic)
  const int row0 = blockIdx.y * 128;    // over T
  const int col0 = blockIdx.x * 128;    // over H
  const int tid = threadIdx.x;
  const int wave = tid >> 6, lane = tid & 63;
  const int wr = wave >> 1, wc = wave & 1;

  f32x4 acc[4][4];
#pragma unroll
  for (int m = 0; m < 4; ++m)
#pragma unroll
    for (int n = 0; n < 4; ++n) {
      f32x4 z = {0.f, 0.f, 0.f, 0.f};
      acc[m][n] = z;
    }

  const int KT = 8 * (l + 1);          // K = 512*(l+1), BK=64
  const int pbase = l * (l + 1) / 2;

  for (int kt = 0; kt < KT; ++kt) {
    const int s = kt >> 3;
    const int f0 = (kt & 7) * 64;
    const short* At = featsbf + (size_t)s * NT * NF + (size_t)row0 * NF + f0;
    const short* Bt = wdbf + (size_t)(pbase + s) * NH * NF + (size_t)col0 * NF + f0;
    stage64(At, NF, As, wave, lane);
    stage64(Bt, NF, Bs, wave, lane);
    __syncthreads();
    mma_step(As, Bs, acc, wr, wc, lane);
    __syncthreads();
  }

  const int lr = (lane >> 4) * 4, lc = lane & 15;
  float* out = recon + (size_t)l * NT * NH;
#pragma unroll
  for (int m = 0; m < 4; ++m) {
#pragma unroll
    for (int n = 0; n < 4; ++n) {
#pragma unroll
      for (int rg = 0; rg < 4; ++rg) {
        const int rr = row0 + wr * 64 + m * 16 + lr + rg;
        const int cc = col0 + wc * 64 + n * 16 + lc;
        out[(size_t)rr * NH + cc] = acc[m][n][rg];
      }
    }
  }
}

// ---------------- launch ----------------

extern "C" void kernel_launch(void* const* d_in, const int* in_sizes, int n_in,
                              void* d_out, int out_size, void* d_ws, size_t ws_size,
                              hipStream_t stream) {
  const float* x = (const float*)d_in[0];     // [L, T, H]
  const float* wenc = (const float*)d_in[1];  // [L, F, H]
  const float* wdec = (const float*)d_in[2];  // [L, L, H, F]

  float* feats_f32 = (float*)d_out;                        // [L, T, F]
  float* recon = feats_f32 + (size_t)NL * NT * NF;         // [L, T, H]

  // workspace layout (bf16 as short):
  //   x_bf   : L*T*H        = 67,108,864  elems (128 MiB)
  //   we_bf  : L*F*H        = 16,777,216  elems ( 32 MiB)
  //   wd_bf  : 136*H*F      = 142,606,336 elems (272 MiB)
  //   ft_bf  : L*T*F        = 16,777,216  elems ( 32 MiB)
  short* x_bf = (short*)d_ws;
  short* we_bf = x_bf + (size_t)NL * NT * NH;
  short* wd_bf = we_bf + (size_t)NL * NF * NH;
  short* ft_bf = wd_bf + (size_t)NPAIR * NH * NF;

  k_cvt_f32_bf16<<<2048, 256, 0, stream>>>(x, x_bf, NL * NT * NH / 4);
  k_cvt_f32_bf16<<<2048, 256, 0, stream>>>(wenc, we_bf, NL * NF * NH / 4);
  k_cvt_wdec<<<dim3(512, NPAIR), 256, 0, stream>>>(wdec, wd_bf);

  k_encode<<<dim3(NF / 128, NT / 128, NL), 256, 0, stream>>>(x_bf, we_bf, feats_f32, ft_bf);
  k_decode<<<dim3(NH / 128, NT / 128, NL), 256, 0, stream>>>(ft_bf, wd_bf, recon);
}

// Round 3
// 911.759 us; speedup vs baseline: 1.0541x; 1.0541x over previous
//
#include <hip/hip_runtime.h>

#define NL 16
#define NT 2048
#define NH 2048
#define NF 512
#define NPAIR 136

typedef short bf16x8 __attribute__((ext_vector_type(8)));
typedef float f32x4 __attribute__((ext_vector_type(4)));
typedef short s16x4 __attribute__((ext_vector_type(4)));

__device__ __forceinline__ short f2bf(float f) {
  union { float f; unsigned u; } x; x.f = f;
  unsigned r = (x.u + 0x7fffu + ((x.u >> 16) & 1u)) >> 16;
  return (short)r;
}

__device__ __forceinline__ int imin(int a, int b) { return a < b ? a : b; }

// ---------------- conversion kernels ----------------

__global__ void k_cvt_f32_bf16(const float* __restrict__ src, short* __restrict__ dst, int n4) {
  int i = blockIdx.x * blockDim.x + threadIdx.x;
  const int stride = gridDim.x * blockDim.x;
  for (; i < n4; i += stride) {
    const float4 v = reinterpret_cast<const float4*>(src)[i];
    s16x4 o;
    o[0] = f2bf(v.x); o[1] = f2bf(v.y); o[2] = f2bf(v.z); o[3] = f2bf(v.w);
    reinterpret_cast<s16x4*>(dst)[i] = o;
  }
}

__global__ void k_cvt_wdec(const float* __restrict__ wdec, short* __restrict__ dst) {
  const int p = blockIdx.y;
  int l = 0;
  while ((l + 1) * (l + 2) / 2 <= p) ++l;
  const int s = p - l * (l + 1) / 2;
  const float* src = wdec + (size_t)(s * NL + l) * (NH * NF);
  short* d = dst + (size_t)p * (NH * NF);
  const int n4 = NH * NF / 4;
  for (int i = blockIdx.x * blockDim.x + threadIdx.x; i < n4; i += gridDim.x * blockDim.x) {
    const float4 v = reinterpret_cast<const float4*>(src)[i];
    s16x4 o;
    o[0] = f2bf(v.x); o[1] = f2bf(v.y); o[2] = f2bf(v.z); o[3] = f2bf(v.w);
    reinterpret_cast<s16x4*>(d)[i] = o;
  }
}

// ---------------- 256x256 8-phase GEMM machinery ----------------
// Tile: BM=BN=256, BK=64. 8 waves (wr=wave>>2 in {0,1}, wc=wave&3 in {0..3}).
// Per-wave output 128x64, split in quadrants (qa,qb): qa picks 64 rows, qb 32 cols.
// LDS: lds[buf][slot][8192 shorts]; slot 0=A-half0, 1=A-half1, 2=B-half0, 3=B-half1.
// Swizzle: element (r, cbyte) lives at LDS byte ((r<<7)|cbyte) ^ ((r&7)<<4).
// Stage schedule per K-tile u (phases p0..p3):
//   p0 reads A0,B0; stages B1(u+1).  p1 reads A0,B1; stages A1(u+1).
//   p2 reads A1,B0; stages A0(u+2).  p3 reads A1,B1; stages B0(u+2).
// EVERY phase issues exactly one stage (2 loads/thread); tail stages clamp the
// source K-tile to KT-1 (target slots provably never read again), preserving
// the uniform-issue invariant that makes per-phase vmcnt(8) (= newest 4 stages
// may be in flight) a sufficient guarantee for every read, including the tail.

__device__ __forceinline__ bf16x8 lds_frag(const short* slot, int r, int cbyte) {
  int byte = (r << 7) + cbyte;
  byte ^= (r & 7) << 4;
  return *reinterpret_cast<const bf16x8*>(reinterpret_cast<const char*>(slot) + byte);
}

__device__ __forceinline__ void stage_half(short* slot, const short* gbase, int ld,
                                           int isA, int h, int tid, int wave) {
#pragma unroll
  for (int j = 0; j < 2; ++j) {
    const int o = j * 8192 + tid * 16;              // linear LDS byte offset in slot
    const int r = o >> 7;                           // slot-local row
    const int cb = (o ^ ((r & 7) << 4)) & 127;      // pre-swizzled source col-byte
    const int g = isA ? (((r >> 6) << 7) + h * 64 + (r & 63))
                      : (((r >> 5) << 6) + h * 32 + (r & 31));
    __builtin_amdgcn_global_load_lds(
        (const __attribute__((address_space(1))) void*)(gbase + (size_t)g * ld + (cb >> 1)),
        (__attribute__((address_space(3))) void*)((char*)slot + j * 8192 + wave * 1024),
        16, 0, 0);
  }
}

template <int QA, int QB, typename StageFn>
__device__ __forceinline__ void phase(short (*bufc)[8192], f32x4 (&acc)[2][2][4][2],
                                      int wr, int wc, int lane, StageFn stage) {
  const int lr = lane & 15;
  const int ko = (lane >> 4) * 16;  // byte offset of this lane's k-chunk
  bf16x8 af[2][4];
  bf16x8 bfr[2][2];
#pragma unroll
  for (int kk = 0; kk < 2; ++kk) {
#pragma unroll
    for (int m = 0; m < 4; ++m)
      af[kk][m] = lds_frag(bufc[QA], wr * 64 + m * 16 + lr, kk * 64 + ko);
#pragma unroll
    for (int n = 0; n < 2; ++n)
      bfr[kk][n] = lds_frag(bufc[2 + QB], wc * 32 + n * 16 + lr, kk * 64 + ko);
  }
  stage();
  __builtin_amdgcn_s_barrier();
  __builtin_amdgcn_s_setprio(1);
#pragma unroll
  for (int kk = 0; kk < 2; ++kk)
#pragma unroll
    for (int m = 0; m < 4; ++m)
#pragma unroll
      for (int n = 0; n < 2; ++n)
        acc[QA][QB][m][n] = __builtin_amdgcn_mfma_f32_16x16x32_bf16(
            af[kk][m], bfr[kk][n], acc[QA][QB][m][n], 0, 0, 0);
  __builtin_amdgcn_s_setprio(0);
  asm volatile("s_waitcnt vmcnt(8)" ::: "memory");
  __builtin_amdgcn_s_barrier();
}

// ---------------- encode: feats[l] = relu(x[l] @ W_enc[l]^T) ----------------

__global__ __launch_bounds__(512) void k_encode256(const short* __restrict__ xbf,
                                                   const short* __restrict__ webf,
                                                   float* __restrict__ feats_f32,
                                                   short* __restrict__ feats_bf) {
  __shared__ short lds[2][4][8192];
  const int l = blockIdx.z;
  const int row0 = blockIdx.y * 256;  // T
  const int col0 = blockIdx.x * 256;  // F
  const int tid = threadIdx.x;
  const int wave = tid >> 6, lane = tid & 63;
  const int wr = wave >> 2, wc = wave & 3;

  const short* A = xbf + (size_t)l * NT * NH + (size_t)row0 * NH;
  const short* B = webf + (size_t)l * NF * NH + (size_t)col0 * NH;

  f32x4 acc[2][2][4][2];
#pragma unroll
  for (int qa = 0; qa < 2; ++qa)
#pragma unroll
    for (int qb = 0; qb < 2; ++qb)
#pragma unroll
      for (int m = 0; m < 4; ++m)
#pragma unroll
        for (int n = 0; n < 2; ++n) {
          f32x4 z = {0.f, 0.f, 0.f, 0.f};
          acc[qa][qb][m][n] = z;
        }

  const int KT = NH / 64;  // 32
  stage_half(lds[0][0], A, NH, 1, 0, tid, wave);
  stage_half(lds[0][2], B, NH, 0, 0, tid, wave);
  stage_half(lds[0][1], A, NH, 1, 1, tid, wave);
  stage_half(lds[0][3], B, NH, 0, 1, tid, wave);
  stage_half(lds[1][0], A + 64, NH, 1, 0, tid, wave);
  stage_half(lds[1][2], B + 64, NH, 0, 0, tid, wave);
  asm volatile("s_waitcnt vmcnt(4)" ::: "memory");
  __builtin_amdgcn_s_barrier();

  for (int u = 0; u < KT; ++u) {
    short(*bufc)[8192] = lds[u & 1];
    short(*bufn)[8192] = lds[(u + 1) & 1];
    phase<0, 0>(bufc, acc, wr, wc, lane, [&] {
      stage_half(bufn[3], B + imin(u + 1, KT - 1) * 64, NH, 0, 1, tid, wave);
    });
    phase<0, 1>(bufc, acc, wr, wc, lane, [&] {
      stage_half(bufn[1], A + imin(u + 1, KT - 1) * 64, NH, 1, 1, tid, wave);
    });
    phase<1, 0>(bufc, acc, wr, wc, lane, [&] {
      stage_half(bufc[0], A + imin(u + 2, KT - 1) * 64, NH, 1, 0, tid, wave);
    });
    phase<1, 1>(bufc, acc, wr, wc, lane, [&] {
      stage_half(bufc[2], B + imin(u + 2, KT - 1) * 64, NH, 0, 0, tid, wave);
    });
  }

  const int lr4 = (lane >> 4) * 4, lc = lane & 15;
  float* outF = feats_f32 + (size_t)l * NT * NF;
  short* outB = feats_bf + (size_t)l * NT * NF;
#pragma unroll
  for (int qa = 0; qa < 2; ++qa)
#pragma unroll
    for (int qb = 0; qb < 2; ++qb)
#pragma unroll
      for (int m = 0; m < 4; ++m)
#pragma unroll
        for (int n = 0; n < 2; ++n)
#pragma unroll
          for (int rg = 0; rg < 4; ++rg) {
            const int rr = row0 + wr * 128 + qa * 64 + m * 16 + lr4 + rg;
            const int cc = col0 + wc * 64 + qb * 32 + n * 16 + lc;
            float v = acc[qa][qb][m][n][rg];
            v = v > 0.f ? v : 0.f;
            outF[(size_t)rr * NF + cc] = v;
            outB[(size_t)rr * NF + cc] = f2bf(v);
          }
}

// ---------------- decode: recon[l] = sum_{s<=l} feats[s] @ W_dec[s,l]^T ----------------

__global__ __launch_bounds__(512) void k_decode256(const short* __restrict__ featsbf,
                                                   const short* __restrict__ wdbf,
                                                   float* __restrict__ recon) {
  __shared__ short lds[2][4][8192];
  // balance permutation: rounds {16,15,2,1},{14,13,4,3},{12,11,6,5},{10,9,8,7} (as l+1)
  const int zg = blockIdx.z >> 2, zi = blockIdx.z & 3;
  const int l = (zi < 2) ? (15 - 2 * zg - zi) : (2 * zg + 3 - zi);
  const int row0 = blockIdx.y * 256;  // T
  const int col0 = blockIdx.x * 256;  // H
  const int tid = threadIdx.x;
  const int wave = tid >> 6, lane = tid & 63;
  const int wr = wave >> 2, wc = wave & 3;
  const int pbase = l * (l + 1) / 2;

  const short* Af = featsbf + (size_t)row0 * NF;
  const short* Bw = wdbf + (size_t)col0 * NF;

  f32x4 acc[2][2][4][2];
#pragma unroll
  for (int qa = 0; qa < 2; ++qa)
#pragma unroll
    for (int qb = 0; qb < 2; ++qb)
#pragma unroll
      for (int m = 0; m < 4; ++m)
#pragma unroll
        for (int n = 0; n < 2; ++n) {
          f32x4 z = {0.f, 0.f, 0.f, 0.f};
          acc[qa][qb][m][n] = z;
        }

  const int KT = 8 * (l + 1);
#define ABASE(kt) (Af + (size_t)((kt) >> 3) * (NT * NF) + ((kt)&7) * 64)
#define BBASE(kt) (Bw + (size_t)(pbase + ((kt) >> 3)) * (NH * NF) + ((kt)&7) * 64)

  stage_half(lds[0][0], ABASE(0), NF, 1, 0, tid, wave);
  stage_half(lds[0][2], BBASE(0), NF, 0, 0, tid, wave);
  stage_half(lds[0][1], ABASE(0), NF, 1, 1, tid, wave);
  stage_half(lds[0][3], BBASE(0), NF, 0, 1, tid, wave);
  stage_half(lds[1][0], ABASE(1), NF, 1, 0, tid, wave);
  stage_half(lds[1][2], BBASE(1), NF, 0, 0, tid, wave);
  asm volatile("s_waitcnt vmcnt(4)" ::: "memory");
  __builtin_amdgcn_s_barrier();

  for (int u = 0; u < KT; ++u) {
    short(*bufc)[8192] = lds[u & 1];
    short(*bufn)[8192] = lds[(u + 1) & 1];
    phase<0, 0>(bufc, acc, wr, wc, lane, [&] {
      stage_half(bufn[3], BBASE(imin(u + 1, KT - 1)), NF, 0, 1, tid, wave);
    });
    phase<0, 1>(bufc, acc, wr, wc, lane, [&] {
      stage_half(bufn[1], ABASE(imin(u + 1, KT - 1)), NF, 1, 1, tid, wave);
    });
    phase<1, 0>(bufc, acc, wr, wc, lane, [&] {
      stage_half(bufc[0], ABASE(imin(u + 2, KT - 1)), NF, 1, 0, tid, wave);
    });
    phase<1, 1>(bufc, acc, wr, wc, lane, [&] {
      stage_half(bufc[2], BBASE(imin(u + 2, KT - 1)), NF, 0, 0, tid, wave);
    });
  }
#undef ABASE
#undef BBASE

  const int lr4 = (lane >> 4) * 4, lc = lane & 15;
  float* out = recon + (size_t)l * NT * NH;
#pragma unroll
  for (int qa = 0; qa < 2; ++qa)
#pragma unroll
    for (int qb = 0; qb < 2; ++qb)
#pragma unroll
      for (int m = 0; m < 4; ++m)
#pragma unroll
        for (int n = 0; n < 2; ++n)
#pragma unroll
          for (int rg = 0; rg < 4; ++rg) {
            const int rr = row0 + wr * 128 + qa * 64 + m * 16 + lr4 + rg;
            const int cc = col0 + wc * 64 + qb * 32 + n * 16 + lc;
            out[(size_t)rr * NH + cc] = acc[qa][qb][m][n][rg];
          }
}

// ---------------- launch ----------------

extern "C" void kernel_launch(void* const* d_in, const int* in_sizes, int n_in,
                              void* d_out, int out_size, void* d_ws, size_t ws_size,
                              hipStream_t stream) {
  const float* x = (const float*)d_in[0];
  const float* wenc = (const float*)d_in[1];
  const float* wdec = (const float*)d_in[2];

  float* feats_f32 = (float*)d_out;
  float* recon = feats_f32 + (size_t)NL * NT * NF;

  short* x_bf = (short*)d_ws;
  short* we_bf = x_bf + (size_t)NL * NT * NH;
  short* wd_bf = we_bf + (size_t)NL * NF * NH;
  short* ft_bf = wd_bf + (size_t)NPAIR * NH * NF;

  k_cvt_f32_bf16<<<2048, 256, 0, stream>>>(x, x_bf, NL * NT * NH / 4);
  k_cvt_f32_bf16<<<2048, 256, 0, stream>>>(wenc, we_bf, NL * NF * NH / 4);
  k_cvt_wdec<<<dim3(512, NPAIR), 256, 0, stream>>>(wdec, wd_bf);

  k_encode256<<<dim3(2, 8, 16), 512, 0, stream>>>(x_bf, we_bf, feats_f32, ft_bf);
  k_decode256<<<dim3(8, 8, 16), 512, 0, stream>>>(ft_bf, wd_bf, recon);
}

// Round 4
// 893.939 us; speedup vs baseline: 1.0751x; 1.0199x over previous
//
#include <hip/hip_runtime.h>

#define NL 16
#define NT 2048
#define NH 2048
#define NF 512
#define NPAIR 136

typedef short bf16x8 __attribute__((ext_vector_type(8)));
typedef float f32x4 __attribute__((ext_vector_type(4)));
typedef short s16x4 __attribute__((ext_vector_type(4)));

__device__ __forceinline__ short f2bf(float f) {
  union { float f; unsigned u; } x; x.f = f;
  unsigned r = (x.u + 0x7fffu + ((x.u >> 16) & 1u)) >> 16;
  return (short)r;
}

__device__ __forceinline__ int imin(int a, int b) { return a < b ? a : b; }

// ---------------- conversion kernels ----------------

__global__ void k_cvt_f32_bf16(const float* __restrict__ src, short* __restrict__ dst, int n4) {
  int i = blockIdx.x * blockDim.x + threadIdx.x;
  const int stride = gridDim.x * blockDim.x;
  for (; i < n4; i += stride) {
    const float4 v = reinterpret_cast<const float4*>(src)[i];
    s16x4 o;
    o[0] = f2bf(v.x); o[1] = f2bf(v.y); o[2] = f2bf(v.z); o[3] = f2bf(v.w);
    reinterpret_cast<s16x4*>(dst)[i] = o;
  }
}

__global__ void k_cvt_wdec(const float* __restrict__ wdec, short* __restrict__ dst) {
  const int p = blockIdx.y;
  int l = 0;
  while ((l + 1) * (l + 2) / 2 <= p) ++l;
  const int s = p - l * (l + 1) / 2;
  const float* src = wdec + (size_t)(s * NL + l) * (NH * NF);
  short* d = dst + (size_t)p * (NH * NF);
  const int n4 = NH * NF / 4;
  for (int i = blockIdx.x * blockDim.x + threadIdx.x; i < n4; i += gridDim.x * blockDim.x) {
    const float4 v = reinterpret_cast<const float4*>(src)[i];
    s16x4 o;
    o[0] = f2bf(v.x); o[1] = f2bf(v.y); o[2] = f2bf(v.z); o[3] = f2bf(v.w);
    reinterpret_cast<s16x4*>(d)[i] = o;
  }
}

// ---------------- 256x256 GEMM machinery (single-barrier phases) ----------------
// Tile: BM=BN=256, BK=64. 8 waves (wr=wave>>2 in {0,1}, wc=wave&3 in {0..3}).
// Per-wave output 128x64, quadrants (qa,qb): qa picks 64 rows, qb 32 cols.
// LDS: lds[buf][slot][8192 shorts]; slot 0=A-half0, 1=A-half1, 2=B-half0, 3=B-half1.
// Swizzle: element (r, cbyte) lives at LDS byte ((r<<7)|cbyte) ^ ((r&7)<<4).
// Phase = { issue 1 stage (2 gload_lds) ; 6 ds_read_b128 ; 16 MFMA ;
//           s_waitcnt vmcnt(8) ; s_barrier }   -- ONE barrier per phase.
// Ledger (end-barriers only):
//  - WAR: slot overwritten by stage(P) was last read in P-1; every wave's
//    reads are consumed (lgkm-wait before its MFMAs) before it reaches the
//    end barrier of P-1; the overwrite is issued after that barrier. Safe.
//  - RAW: stage issued at P is retired by vmcnt(8) at end of P+4 (phases
//    P+1..P+4 issue exactly the 8 newer loads — tail clamps keep issue
//    uniform), first read at P+5. Safe.

__device__ __forceinline__ bf16x8 lds_frag(const short* slot, int r, int cbyte) {
  int byte = (r << 7) + cbyte;
  byte ^= (r & 7) << 4;
  return *reinterpret_cast<const bf16x8*>(reinterpret_cast<const char*>(slot) + byte);
}

__device__ __forceinline__ void stage_half(short* slot, const short* gbase, int ld,
                                           int isA, int h, int tid, int wave) {
#pragma unroll
  for (int j = 0; j < 2; ++j) {
    const int o = j * 8192 + tid * 16;              // linear LDS byte offset in slot
    const int r = o >> 7;                           // slot-local row
    const int cb = (o ^ ((r & 7) << 4)) & 127;      // pre-swizzled source col-byte
    const int g = isA ? (((r >> 6) << 7) + h * 64 + (r & 63))
                      : (((r >> 5) << 6) + h * 32 + (r & 31));
    __builtin_amdgcn_global_load_lds(
        (const __attribute__((address_space(1))) void*)(gbase + (size_t)g * ld + (cb >> 1)),
        (__attribute__((address_space(3))) void*)((char*)slot + j * 8192 + wave * 1024),
        16, 0, 0);
  }
}

template <int QA, int QB, typename StageFn>
__device__ __forceinline__ void phase(short (*bufc)[8192], f32x4 (&acc)[2][2][4][2],
                                      int wr, int wc, int lane, StageFn stage) {
  const int lr = lane & 15;
  const int ko = (lane >> 4) * 16;  // byte offset of this lane's k-chunk
  stage();                          // issue global loads earliest in the phase
  bf16x8 af[2][4];
  bf16x8 bfr[2][2];
#pragma unroll
  for (int kk = 0; kk < 2; ++kk) {
#pragma unroll
    for (int m = 0; m < 4; ++m)
      af[kk][m] = lds_frag(bufc[QA], wr * 64 + m * 16 + lr, kk * 64 + ko);
#pragma unroll
    for (int n = 0; n < 2; ++n)
      bfr[kk][n] = lds_frag(bufc[2 + QB], wc * 32 + n * 16 + lr, kk * 64 + ko);
  }
  __builtin_amdgcn_s_setprio(1);
#pragma unroll
  for (int kk = 0; kk < 2; ++kk)
#pragma unroll
    for (int m = 0; m < 4; ++m)
#pragma unroll
      for (int n = 0; n < 2; ++n)
        acc[QA][QB][m][n] = __builtin_amdgcn_mfma_f32_16x16x32_bf16(
            af[kk][m], bfr[kk][n], acc[QA][QB][m][n], 0, 0, 0);
  __builtin_amdgcn_s_setprio(0);
  asm volatile("s_waitcnt vmcnt(8)" ::: "memory");
  __builtin_amdgcn_s_barrier();
}

// ---------------- encode: feats[l] = relu(x[l] @ W_enc[l]^T) ----------------

__global__ __launch_bounds__(512) void k_encode256(const short* __restrict__ xbf,
                                                   const short* __restrict__ webf,
                                                   float* __restrict__ feats_f32,
                                                   short* __restrict__ feats_bf) {
  __shared__ short lds[2][4][8192];
  const int l = blockIdx.z;
  const int row0 = blockIdx.y * 256;  // T
  const int col0 = blockIdx.x * 256;  // F
  const int tid = threadIdx.x;
  const int wave = tid >> 6, lane = tid & 63;
  const int wr = wave >> 2, wc = wave & 3;

  const short* A = xbf + (size_t)l * NT * NH + (size_t)row0 * NH;
  const short* B = webf + (size_t)l * NF * NH + (size_t)col0 * NH;

  f32x4 acc[2][2][4][2];
#pragma unroll
  for (int qa = 0; qa < 2; ++qa)
#pragma unroll
    for (int qb = 0; qb < 2; ++qb)
#pragma unroll
      for (int m = 0; m < 4; ++m)
#pragma unroll
        for (int n = 0; n < 2; ++n) {
          f32x4 z = {0.f, 0.f, 0.f, 0.f};
          acc[qa][qb][m][n] = z;
        }

  const int KT = NH / 64;  // 32
  stage_half(lds[0][0], A, NH, 1, 0, tid, wave);
  stage_half(lds[0][2], B, NH, 0, 0, tid, wave);
  stage_half(lds[0][1], A, NH, 1, 1, tid, wave);
  stage_half(lds[0][3], B, NH, 0, 1, tid, wave);
  stage_half(lds[1][0], A + 64, NH, 1, 0, tid, wave);
  stage_half(lds[1][2], B + 64, NH, 0, 0, tid, wave);
  asm volatile("s_waitcnt vmcnt(4)" ::: "memory");
  __builtin_amdgcn_s_barrier();

  for (int u = 0; u < KT; ++u) {
    short(*bufc)[8192] = lds[u & 1];
    short(*bufn)[8192] = lds[(u + 1) & 1];
    phase<0, 0>(bufc, acc, wr, wc, lane, [&] {
      stage_half(bufn[3], B + imin(u + 1, KT - 1) * 64, NH, 0, 1, tid, wave);
    });
    phase<0, 1>(bufc, acc, wr, wc, lane, [&] {
      stage_half(bufn[1], A + imin(u + 1, KT - 1) * 64, NH, 1, 1, tid, wave);
    });
    phase<1, 0>(bufc, acc, wr, wc, lane, [&] {
      stage_half(bufc[0], A + imin(u + 2, KT - 1) * 64, NH, 1, 0, tid, wave);
    });
    phase<1, 1>(bufc, acc, wr, wc, lane, [&] {
      stage_half(bufc[2], B + imin(u + 2, KT - 1) * 64, NH, 0, 0, tid, wave);
    });
  }

  const int lr4 = (lane >> 4) * 4, lc = lane & 15;
  float* outF = feats_f32 + (size_t)l * NT * NF;
  short* outB = feats_bf + (size_t)l * NT * NF;
#pragma unroll
  for (int qa = 0; qa < 2; ++qa)
#pragma unroll
    for (int qb = 0; qb < 2; ++qb)
#pragma unroll
      for (int m = 0; m < 4; ++m)
#pragma unroll
        for (int n = 0; n < 2; ++n)
#pragma unroll
          for (int rg = 0; rg < 4; ++rg) {
            const int rr = row0 + wr * 128 + qa * 64 + m * 16 + lr4 + rg;
            const int cc = col0 + wc * 64 + qb * 32 + n * 16 + lc;
            float v = acc[qa][qb][m][n][rg];
            v = v > 0.f ? v : 0.f;
            outF[(size_t)rr * NF + cc] = v;
            outB[(size_t)rr * NF + cc] = f2bf(v);
          }
}

// ---------------- decode: recon[l] = sum_{s<=l} feats[s] @ W_dec[s,l]^T ----------------

__global__ __launch_bounds__(512) void k_decode256(const short* __restrict__ featsbf,
                                                   const short* __restrict__ wdbf,
                                                   float* __restrict__ recon) {
  __shared__ short lds[2][4][8192];
  const int l = (NL - 1) - blockIdx.z;  // heavy-first (LPT under in-order dispatch)
  const int row0 = blockIdx.y * 256;    // T
  const int col0 = blockIdx.x * 256;    // H
  const int tid = threadIdx.x;
  const int wave = tid >> 6, lane = tid & 63;
  const int wr = wave >> 2, wc = wave & 3;
  const int pbase = l * (l + 1) / 2;

  const short* Af = featsbf + (size_t)row0 * NF;
  const short* Bw = wdbf + (size_t)col0 * NF;

  f32x4 acc[2][2][4][2];
#pragma unroll
  for (int qa = 0; qa < 2; ++qa)
#pragma unroll
    for (int qb = 0; qb < 2; ++qb)
#pragma unroll
      for (int m = 0; m < 4; ++m)
#pragma unroll
        for (int n = 0; n < 2; ++n) {
          f32x4 z = {0.f, 0.f, 0.f, 0.f};
          acc[qa][qb][m][n] = z;
        }

  const int KT = 8 * (l + 1);
#define ABASE(kt) (Af + (size_t)((kt) >> 3) * (NT * NF) + ((kt)&7) * 64)
#define BBASE(kt) (Bw + (size_t)(pbase + ((kt) >> 3)) * (NH * NF) + ((kt)&7) * 64)

  stage_half(lds[0][0], ABASE(0), NF, 1, 0, tid, wave);
  stage_half(lds[0][2], BBASE(0), NF, 0, 0, tid, wave);
  stage_half(lds[0][1], ABASE(0), NF, 1, 1, tid, wave);
  stage_half(lds[0][3], BBASE(0), NF, 0, 1, tid, wave);
  stage_half(lds[1][0], ABASE(1), NF, 1, 0, tid, wave);
  stage_half(lds[1][2], BBASE(1), NF, 0, 0, tid, wave);
  asm volatile("s_waitcnt vmcnt(4)" ::: "memory");
  __builtin_amdgcn_s_barrier();

  for (int u = 0; u < KT; ++u) {
    short(*bufc)[8192] = lds[u & 1];
    short(*bufn)[8192] = lds[(u + 1) & 1];
    phase<0, 0>(bufc, acc, wr, wc, lane, [&] {
      stage_half(bufn[3], BBASE(imin(u + 1, KT - 1)), NF, 0, 1, tid, wave);
    });
    phase<0, 1>(bufc, acc, wr, wc, lane, [&] {
      stage_half(bufn[1], ABASE(imin(u + 1, KT - 1)), NF, 1, 1, tid, wave);
    });
    phase<1, 0>(bufc, acc, wr, wc, lane, [&] {
      stage_half(bufc[0], ABASE(imin(u + 2, KT - 1)), NF, 1, 0, tid, wave);
    });
    phase<1, 1>(bufc, acc, wr, wc, lane, [&] {
      stage_half(bufc[2], BBASE(imin(u + 2, KT - 1)), NF, 0, 0, tid, wave);
    });
  }
#undef ABASE
#undef BBASE

  const int lr4 = (lane >> 4) * 4, lc = lane & 15;
  float* out = recon + (size_t)l * NT * NH;
#pragma unroll
  for (int qa = 0; qa < 2; ++qa)
#pragma unroll
    for (int qb = 0; qb < 2; ++qb)
#pragma unroll
      for (int m = 0; m < 4; ++m)
#pragma unroll
        for (int n = 0; n < 2; ++n)
#pragma unroll
          for (int rg = 0; rg < 4; ++rg) {
            const int rr = row0 + wr * 128 + qa * 64 + m * 16 + lr4 + rg;
            const int cc = col0 + wc * 64 + qb * 32 + n * 16 + lc;
            out[(size_t)rr * NH + cc] = acc[qa][qb][m][n][rg];
          }
}

// ---------------- launch ----------------

extern "C" void kernel_launch(void* const* d_in, const int* in_sizes, int n_in,
                              void* d_out, int out_size, void* d_ws, size_t ws_size,
                              hipStream_t stream) {
  const float* x = (const float*)d_in[0];
  const float* wenc = (const float*)d_in[1];
  const float* wdec = (const float*)d_in[2];

  float* feats_f32 = (float*)d_out;
  float* recon = feats_f32 + (size_t)NL * NT * NF;

  short* x_bf = (short*)d_ws;
  short* we_bf = x_bf + (size_t)NL * NT * NH;
  short* wd_bf = we_bf + (size_t)NL * NF * NH;
  short* ft_bf = wd_bf + (size_t)NPAIR * NH * NF;

  k_cvt_f32_bf16<<<2048, 256, 0, stream>>>(x, x_bf, NL * NT * NH / 4);
  k_cvt_f32_bf16<<<2048, 256, 0, stream>>>(wenc, we_bf, NL * NF * NH / 4);
  k_cvt_wdec<<<dim3(512, NPAIR), 256, 0, stream>>>(wdec, wd_bf);

  k_encode256<<<dim3(2, 8, 16), 512, 0, stream>>>(x_bf, we_bf, feats_f32, ft_bf);
  k_decode256<<<dim3(8, 8, 16), 512, 0, stream>>>(ft_bf, wd_bf, recon);
}

// Round 5
// 830.752 us; speedup vs baseline: 1.1569x; 1.0761x over previous
//
#include <hip/hip_runtime.h>

#define NL 16
#define NT 2048
#define NH 2048
#define NF 512
#define NPAIR 136

typedef short bf16x8 __attribute__((ext_vector_type(8)));
typedef float f32x4 __attribute__((ext_vector_type(4)));
typedef short s16x4 __attribute__((ext_vector_type(4)));

__device__ __forceinline__ short f2bf(float f) {
  union { float f; unsigned u; } x; x.f = f;
  unsigned r = (x.u + 0x7fffu + ((x.u >> 16) & 1u)) >> 16;
  return (short)r;
}

__device__ __forceinline__ int imin(int a, int b) { return a < b ? a : b; }

// ---------------- conversion kernels ----------------

__global__ void k_cvt_f32_bf16(const float* __restrict__ src, short* __restrict__ dst, int n4) {
  int i = blockIdx.x * blockDim.x + threadIdx.x;
  const int stride = gridDim.x * blockDim.x;
  for (; i < n4; i += stride) {
    const float4 v = reinterpret_cast<const float4*>(src)[i];
    s16x4 o;
    o[0] = f2bf(v.x); o[1] = f2bf(v.y); o[2] = f2bf(v.z); o[3] = f2bf(v.w);
    reinterpret_cast<s16x4*>(dst)[i] = o;
  }
}

__global__ void k_cvt_wdec(const float* __restrict__ wdec, short* __restrict__ dst) {
  const int p = blockIdx.y;
  int l = 0;
  while ((l + 1) * (l + 2) / 2 <= p) ++l;
  const int s = p - l * (l + 1) / 2;
  const float* src = wdec + (size_t)(s * NL + l) * (NH * NF);
  short* d = dst + (size_t)p * (NH * NF);
  const int n4 = NH * NF / 4;
  for (int i = blockIdx.x * blockDim.x + threadIdx.x; i < n4; i += gridDim.x * blockDim.x) {
    const float4 v = reinterpret_cast<const float4*>(src)[i];
    s16x4 o;
    o[0] = f2bf(v.x); o[1] = f2bf(v.y); o[2] = f2bf(v.z); o[3] = f2bf(v.w);
    reinterpret_cast<s16x4*>(d)[i] = o;
  }
}

// ---------------- 256x256 GEMM machinery (frag-cached K-tiles) ----------------
// Tile: BM=BN=256, BK=64. 8 waves (wr=wave>>2 in {0,1}, wc=wave&3 in {0..3}).
// Per-wave output 128x64, quadrants (qa,qb): qa picks 64 rows, qb 32 cols.
// LDS: lds[buf][slot][8192 shorts]; slot 0=A-half0, 1=A-half1, 2=B-half0, 3=B-half1.
// Swizzle: element (r, cbyte) lives at LDS byte ((r<<7)|cbyte) ^ ((r&7)<<4).
// K-tile = 4 sub-phases; fragments are read from LDS ONCE and cached in VGPRs:
//   p0: stage B1(u+1); read A0(12 frags: a0,b0); MFMA q(0,0); vmcnt(8); barrier
//   p1: stage A1(u+1); read b1(4);               MFMA q(0,1); vmcnt(8); barrier
//   p2: stage A0(u+2); read a1(8);               MFMA q(1,0); vmcnt(8); barrier
//   p3: stage B0(u+2); (no reads)                MFMA q(1,1); vmcnt(8); barrier
// This halves LDS read traffic vs re-reading per quadrant (the measured
// bottleneck: 384KB/CU/K-tile > MFMA time; now 192KB < MFMA time).
// Ledger: every ds_read feeds its own sub-phase's MFMA (compiler lgkm-waits it
// before that sub-phase's end barrier), so WAR is safe (slot overwritten by a
// stage at P had its last LDS-read at/before P-1). RAW: stage at P retired by
// vmcnt(8) at end of P+4 (uniform 1-stage-per-phase issue incl. clamped tail),
// first read at P+5.

__device__ __forceinline__ bf16x8 lds_frag(const short* slot, int r, int cbyte) {
  int byte = (r << 7) + cbyte;
  byte ^= (r & 7) << 4;
  return *reinterpret_cast<const bf16x8*>(reinterpret_cast<const char*>(slot) + byte);
}

__device__ __forceinline__ void stage_half(short* slot, const short* gbase, int ld,
                                           int isA, int h, int tid, int wave) {
#pragma unroll
  for (int j = 0; j < 2; ++j) {
    const int o = j * 8192 + tid * 16;              // linear LDS byte offset in slot
    const int r = o >> 7;                           // slot-local row
    const int cb = (o ^ ((r & 7) << 4)) & 127;      // pre-swizzled source col-byte
    const int g = isA ? (((r >> 6) << 7) + h * 64 + (r & 63))
                      : (((r >> 5) << 6) + h * 32 + (r & 31));
    __builtin_amdgcn_global_load_lds(
        (const __attribute__((address_space(1))) void*)(gbase + (size_t)g * ld + (cb >> 1)),
        (__attribute__((address_space(3))) void*)((char*)slot + j * 8192 + wave * 1024),
        16, 0, 0);
  }
}

__device__ __forceinline__ void mma_cluster(f32x4 (&q)[4][2], bf16x8 (&a)[2][4],
                                            bf16x8 (&b)[2][2]) {
  __builtin_amdgcn_s_setprio(1);
#pragma unroll
  for (int kk = 0; kk < 2; ++kk)
#pragma unroll
    for (int m = 0; m < 4; ++m)
#pragma unroll
      for (int n = 0; n < 2; ++n)
        q[m][n] = __builtin_amdgcn_mfma_f32_16x16x32_bf16(a[kk][m], b[kk][n], q[m][n], 0, 0, 0);
  __builtin_amdgcn_s_setprio(0);
}

__device__ __forceinline__ void phase_end() {
  asm volatile("s_waitcnt vmcnt(8)" ::: "memory");
  __builtin_amdgcn_s_barrier();
}

template <typename S0, typename S1, typename S2, typename S3>
__device__ __forceinline__ void ktile(short (*bufc)[8192], f32x4 (&acc)[2][2][4][2],
                                      int wr, int wc, int lane,
                                      S0 s0, S1 s1, S2 s2, S3 s3) {
  const int lr = lane & 15;
  const int ko = (lane >> 4) * 16;  // byte offset of this lane's k-chunk
  bf16x8 a0[2][4], a1[2][4], b0[2][2], b1[2][2];
  // ---- p0: read a0,b0 ; mfma (0,0)
  s0();
#pragma unroll
  for (int kk = 0; kk < 2; ++kk) {
#pragma unroll
    for (int m = 0; m < 4; ++m)
      a0[kk][m] = lds_frag(bufc[0], wr * 64 + m * 16 + lr, kk * 64 + ko);
#pragma unroll
    for (int n = 0; n < 2; ++n)
      b0[kk][n] = lds_frag(bufc[2], wc * 32 + n * 16 + lr, kk * 64 + ko);
  }
  mma_cluster(acc[0][0], a0, b0);
  phase_end();
  // ---- p1: read b1 ; mfma (0,1)
  s1();
#pragma unroll
  for (int kk = 0; kk < 2; ++kk)
#pragma unroll
    for (int n = 0; n < 2; ++n)
      b1[kk][n] = lds_frag(bufc[3], wc * 32 + n * 16 + lr, kk * 64 + ko);
  mma_cluster(acc[0][1], a0, b1);
  phase_end();
  // ---- p2: read a1 ; mfma (1,0)
  s2();
#pragma unroll
  for (int kk = 0; kk < 2; ++kk)
#pragma unroll
    for (int m = 0; m < 4; ++m)
      a1[kk][m] = lds_frag(bufc[1], wr * 64 + m * 16 + lr, kk * 64 + ko);
  mma_cluster(acc[1][0], a1, b0);
  phase_end();
  // ---- p3: no reads ; mfma (1,1)
  s3();
  mma_cluster(acc[1][1], a1, b1);
  phase_end();
}

// ---------------- encode: feats[l] = relu(x[l] @ W_enc[l]^T) ----------------

__global__ __launch_bounds__(512, 2) void k_encode256(const short* __restrict__ xbf,
                                                      const short* __restrict__ webf,
                                                      float* __restrict__ feats_f32,
                                                      short* __restrict__ feats_bf) {
  __shared__ short lds[2][4][8192];
  const int l = blockIdx.z;
  const int row0 = blockIdx.y * 256;  // T
  const int col0 = blockIdx.x * 256;  // F
  const int tid = threadIdx.x;
  const int wave = tid >> 6, lane = tid & 63;
  const int wr = wave >> 2, wc = wave & 3;

  const short* A = xbf + (size_t)l * NT * NH + (size_t)row0 * NH;
  const short* B = webf + (size_t)l * NF * NH + (size_t)col0 * NH;

  f32x4 acc[2][2][4][2];
#pragma unroll
  for (int qa = 0; qa < 2; ++qa)
#pragma unroll
    for (int qb = 0; qb < 2; ++qb)
#pragma unroll
      for (int m = 0; m < 4; ++m)
#pragma unroll
        for (int n = 0; n < 2; ++n) {
          f32x4 z = {0.f, 0.f, 0.f, 0.f};
          acc[qa][qb][m][n] = z;
        }

  const int KT = NH / 64;  // 32
  stage_half(lds[0][0], A, NH, 1, 0, tid, wave);
  stage_half(lds[0][2], B, NH, 0, 0, tid, wave);
  stage_half(lds[0][1], A, NH, 1, 1, tid, wave);
  stage_half(lds[0][3], B, NH, 0, 1, tid, wave);
  stage_half(lds[1][0], A + 64, NH, 1, 0, tid, wave);
  stage_half(lds[1][2], B + 64, NH, 0, 0, tid, wave);
  asm volatile("s_waitcnt vmcnt(4)" ::: "memory");
  __builtin_amdgcn_s_barrier();

  for (int u = 0; u < KT; ++u) {
    short(*bufc)[8192] = lds[u & 1];
    short(*bufn)[8192] = lds[(u + 1) & 1];
    ktile(bufc, acc, wr, wc, lane,
          [&] { stage_half(bufn[3], B + imin(u + 1, KT - 1) * 64, NH, 0, 1, tid, wave); },
          [&] { stage_half(bufn[1], A + imin(u + 1, KT - 1) * 64, NH, 1, 1, tid, wave); },
          [&] { stage_half(bufc[0], A + imin(u + 2, KT - 1) * 64, NH, 1, 0, tid, wave); },
          [&] { stage_half(bufc[2], B + imin(u + 2, KT - 1) * 64, NH, 0, 0, tid, wave); });
  }

  const int lr4 = (lane >> 4) * 4, lc = lane & 15;
  float* outF = feats_f32 + (size_t)l * NT * NF;
  short* outB = feats_bf + (size_t)l * NT * NF;
#pragma unroll
  for (int qa = 0; qa < 2; ++qa)
#pragma unroll
    for (int qb = 0; qb < 2; ++qb)
#pragma unroll
      for (int m = 0; m < 4; ++m)
#pragma unroll
        for (int n = 0; n < 2; ++n)
#pragma unroll
          for (int rg = 0; rg < 4; ++rg) {
            const int rr = row0 + wr * 128 + qa * 64 + m * 16 + lr4 + rg;
            const int cc = col0 + wc * 64 + qb * 32 + n * 16 + lc;
            float v = acc[qa][qb][m][n][rg];
            v = v > 0.f ? v : 0.f;
            outF[(size_t)rr * NF + cc] = v;
            outB[(size_t)rr * NF + cc] = f2bf(v);
          }
}

// ---------------- decode: recon[l] = sum_{s<=l} feats[s] @ W_dec[s,l]^T ----------------

__global__ __launch_bounds__(512, 2) void k_decode256(const short* __restrict__ featsbf,
                                                      const short* __restrict__ wdbf,
                                                      float* __restrict__ recon) {
  __shared__ short lds[2][4][8192];
  const int l = (NL - 1) - blockIdx.z;  // heavy-first (LPT under in-order dispatch)
  const int row0 = blockIdx.y * 256;    // T
  const int col0 = blockIdx.x * 256;    // H
  const int tid = threadIdx.x;
  const int wave = tid >> 6, lane = tid & 63;
  const int wr = wave >> 2, wc = wave & 3;
  const int pbase = l * (l + 1) / 2;

  const short* Af = featsbf + (size_t)row0 * NF;
  const short* Bw = wdbf + (size_t)col0 * NF;

  f32x4 acc[2][2][4][2];
#pragma unroll
  for (int qa = 0; qa < 2; ++qa)
#pragma unroll
    for (int qb = 0; qb < 2; ++qb)
#pragma unroll
      for (int m = 0; m < 4; ++m)
#pragma unroll
        for (int n = 0; n < 2; ++n) {
          f32x4 z = {0.f, 0.f, 0.f, 0.f};
          acc[qa][qb][m][n] = z;
        }

  const int KT = 8 * (l + 1);
#define ABASE(kt) (Af + (size_t)((kt) >> 3) * (NT * NF) + ((kt)&7) * 64)
#define BBASE(kt) (Bw + (size_t)(pbase + ((kt) >> 3)) * (NH * NF) + ((kt)&7) * 64)

  stage_half(lds[0][0], ABASE(0), NF, 1, 0, tid, wave);
  stage_half(lds[0][2], BBASE(0), NF, 0, 0, tid, wave);
  stage_half(lds[0][1], ABASE(0), NF, 1, 1, tid, wave);
  stage_half(lds[0][3], BBASE(0), NF, 0, 1, tid, wave);
  stage_half(lds[1][0], ABASE(1), NF, 1, 0, tid, wave);
  stage_half(lds[1][2], BBASE(1), NF, 0, 0, tid, wave);
  asm volatile("s_waitcnt vmcnt(4)" ::: "memory");
  __builtin_amdgcn_s_barrier();

  for (int u = 0; u < KT; ++u) {
    short(*bufc)[8192] = lds[u & 1];
    short(*bufn)[8192] = lds[(u + 1) & 1];
    ktile(bufc, acc, wr, wc, lane,
          [&] { stage_half(bufn[3], BBASE(imin(u + 1, KT - 1)), NF, 0, 1, tid, wave); },
          [&] { stage_half(bufn[1], ABASE(imin(u + 1, KT - 1)), NF, 1, 1, tid, wave); },
          [&] { stage_half(bufc[0], ABASE(imin(u + 2, KT - 1)), NF, 1, 0, tid, wave); },
          [&] { stage_half(bufc[2], BBASE(imin(u + 2, KT - 1)), NF, 0, 0, tid, wave); });
  }
#undef ABASE
#undef BBASE

  const int lr4 = (lane >> 4) * 4, lc = lane & 15;
  float* out = recon + (size_t)l * NT * NH;
#pragma unroll
  for (int qa = 0; qa < 2; ++qa)
#pragma unroll
    for (int qb = 0; qb < 2; ++qb)
#pragma unroll
      for (int m = 0; m < 4; ++m)
#pragma unroll
        for (int n = 0; n < 2; ++n)
#pragma unroll
          for (int rg = 0; rg < 4; ++rg) {
            const int rr = row0 + wr * 128 + qa * 64 + m * 16 + lr4 + rg;
            const int cc = col0 + wc * 64 + qb * 32 + n * 16 + lc;
            out[(size_t)rr * NH + cc] = acc[qa][qb][m][n][rg];
          }
}

// ---------------- launch ----------------

extern "C" void kernel_launch(void* const* d_in, const int* in_sizes, int n_in,
                              void* d_out, int out_size, void* d_ws, size_t ws_size,
                              hipStream_t stream) {
  const float* x = (const float*)d_in[0];
  const float* wenc = (const float*)d_in[1];
  const float* wdec = (const float*)d_in[2];

  float* feats_f32 = (float*)d_out;
  float* recon = feats_f32 + (size_t)NL * NT * NF;

  short* x_bf = (short*)d_ws;
  short* we_bf = x_bf + (size_t)NL * NT * NH;
  short* wd_bf = we_bf + (size_t)NL * NF * NH;
  short* ft_bf = wd_bf + (size_t)NPAIR * NH * NF;

  k_cvt_f32_bf16<<<2048, 256, 0, stream>>>(x, x_bf, NL * NT * NH / 4);
  k_cvt_f32_bf16<<<2048, 256, 0, stream>>>(wenc, we_bf, NL * NF * NH / 4);
  k_cvt_wdec<<<dim3(512, NPAIR), 256, 0, stream>>>(wdec, wd_bf);

  k_encode256<<<dim3(2, 8, 16), 512, 0, stream>>>(x_bf, we_bf, feats_f32, ft_bf);
  k_decode256<<<dim3(8, 8, 16), 512, 0, stream>>>(ft_bf, wd_bf, recon);
}